// Round 5
// baseline (152.216 us; speedup 1.0000x reference)
//
#include <hip/hip_runtime.h>

typedef __attribute__((ext_vector_type(4))) float float4v;
typedef __attribute__((ext_vector_type(2))) float float2v;
typedef __attribute__((ext_vector_type(8))) short short8;
typedef __attribute__((ext_vector_type(4))) float f32x4;
typedef __attribute__((ext_vector_type(4))) int int4v;

#define NEGV (-1000000000.0f)

// B=64, L=2048, E=512, Q=256; M = 131072, K = 512, N = 512
#define MTOT (64 * 2048)

__device__ __forceinline__ unsigned short f2bf(float f) {
    unsigned int u = __float_as_uint(f);
    u += 0x7fffu + ((u >> 16) & 1u);   // RNE round to bf16
    return (unsigned short)(u >> 16);
}

// async global->LDS, 16B per lane, LDS dest = wave-uniform base + lane*16
__device__ __forceinline__ void gload_lds16(const void* g, void* l) {
    __builtin_amdgcn_global_load_lds(
        (__attribute__((address_space(1))) unsigned int*)(unsigned long long)(g),
        (__attribute__((address_space(3))) unsigned int*)(unsigned int)(unsigned long long)(l),
        16, 0, 0);
}

// Wt[e][c] = bf16(W1[c][e]) via LDS 32x32 tile transpose (coalesced both sides).
__global__ __launch_bounds__(256)
void prep_wt_kernel(const float* __restrict__ W1, unsigned short* __restrict__ Wt) {
    __shared__ float t[32][33];
    int bx = blockIdx.x & 15;    // c tile
    int by = blockIdx.x >> 4;    // e tile
    int tx = threadIdx.x & 31;
    int ty = threadIdx.x >> 5;   // 0..7
    #pragma unroll
    for (int i = 0; i < 4; ++i)
        t[ty + 8 * i][tx] = W1[(bx * 32 + ty + 8 * i) * 512 + by * 32 + tx];
    __syncthreads();
    #pragma unroll
    for (int i = 0; i < 4; ++i)
        Wt[(by * 32 + ty + 8 * i) * 512 + bx * 32 + tx] = f2bf(t[tx][ty + 8 * i]);
}

// qc[b][e] = b1[e] + sum_q query[b][q] * W1[512+q][e]
__global__ void prep_qc_kernel(const float* __restrict__ query, const float* __restrict__ W1,
                               const float* __restrict__ b1, float* __restrict__ qc) {
    int b = blockIdx.x;
    int e = threadIdx.x;           // 256 threads -> cols e and e+256
    float acc0 = b1[e];
    float acc1 = b1[e + 256];
    const float* w = W1 + 512 * 512;
    for (int q = 0; q < 256; ++q) {
        float qv = query[b * 256 + q];
        acc0 += qv * w[q * 512 + e];
        acc1 += qv * w[q * 512 + e + 256];
    }
    qc[b * 512 + e] = acc0;
    qc[b * 512 + e + 256] = acc1;
}

// 128x128 tile, BK=32, 4 waves. 3-buffer LDS ring, counted vmcnt (T4):
// loads for K-step t complete by step t+2's wait; never drained to 0 in-loop.
// A f32 XOR-swizzled (r&7)<<4; B bf16 XOR-swizzled ((r>>1)&3)<<4.
__global__ __launch_bounds__(256)
void gemm_logits_kernel(const float* __restrict__ A,            // encoded [M][512] f32
                        const unsigned short* __restrict__ Wt,  // [512 n][512 k] bf16
                        const float* __restrict__ qc,           // [64][512]
                        const float* __restrict__ v,            // [512]
                        const int* __restrict__ length,         // [64]
                        float* __restrict__ part)               // [8][M] partial logits
{
    // XCD swizzle, load-balanced: XCD x gets bm = {x, x+8, x+16, ...} (random
    // per-batch lengths spread evenly); the 4 bn of one bm sit 8 bids apart
    // (same XCD, dispatch-adjacent) -> A-tile L2 reuse.
    int bid = blockIdx.x;
    int x = bid & 7;
    int j = bid >> 3;              // 0..511
    int bm = (j >> 2) * 8 + x;     // 0..1023 row tile
    int bn = j & 3;                // 0..3   N slice
    int b = bm >> 4;
    int l0 = (bm & 15) * 128;
    if (l0 >= length[b]) return;   // fully-masked tile

    __shared__ float As[3 * 128 * 32];           // 3 x 16 KB
    __shared__ unsigned short Bs[3 * 128 * 32];  // 3 x 8 KB

    int tid = threadIdx.x;
    int lane = tid & 63;
    int w = tid >> 6;
    int wm = w >> 1, wn = w & 1;
    long row0 = (long)bm * 128;
    int col0 = bn * 128;

    // staging: LDS linear dest, global pre-swizzled source (m173 pattern)
    const char* gA[4];
    const char* gB[2];
    #pragma unroll
    for (int i = 0; i < 4; ++i) {
        int off = (w * 4 + i) * 1024 + lane * 16;   // linear LDS byte in A buf
        int r = off >> 7;                            // 128B per row (32 f32)
        int kbg = (off & 127) ^ ((r & 7) << 4);      // inverse swizzle on source
        gA[i] = (const char*)A + (row0 + r) * 2048 + kbg;
    }
    #pragma unroll
    for (int i = 0; i < 2; ++i) {
        int off = (w * 2 + i) * 1024 + lane * 16;   // 64B per row (32 bf16)
        int r = off >> 6;
        int kbg = (off & 63) ^ (((r >> 1) & 3) << 4);
        gB[i] = (const char*)Wt + (long)(col0 + r) * 1024 + kbg;
    }

    // fragment read byte offsets (within one buffer)
    int aoff[4][2], boff[4];
    int kb0 = 32 * (lane >> 4);
    #pragma unroll
    for (int mi = 0; mi < 4; ++mi) {
        int ar = wm * 64 + (lane & 15) + mi * 16;
        int swz = (ar & 7) << 4;
        aoff[mi][0] = ar * 128 + (kb0 ^ swz);
        aoff[mi][1] = ar * 128 + ((kb0 + 16) ^ swz);
    }
    int kbB = 16 * (lane >> 4);
    #pragma unroll
    for (int ni = 0; ni < 4; ++ni) {
        int br = wn * 64 + (lane & 15) + ni * 16;
        boff[ni] = br * 64 + (kbB ^ (((br >> 1) & 3) << 4));
    }

    f32x4 acc[4][4] = {};

    auto STAGE = [&](int t, char* la, char* lb) {   // 6 vmem instr per wave
        gload_lds16(gA[0] + t * 128, la + w * 4096);
        gload_lds16(gA[1] + t * 128, la + w * 4096 + 1024);
        gload_lds16(gA[2] + t * 128, la + w * 4096 + 2048);
        gload_lds16(gA[3] + t * 128, la + w * 4096 + 3072);
        gload_lds16(gB[0] + t * 64, lb + w * 2048);
        gload_lds16(gB[1] + t * 64, lb + w * 2048 + 1024);
    };
    auto COMPUTE = [&](const char* as, const char* bs) {
        short8 af[4], bf[4];
        #pragma unroll
        for (int mi = 0; mi < 4; ++mi) {
            float4v xv = *(const float4v*)(as + aoff[mi][0]);
            float4v yv = *(const float4v*)(as + aoff[mi][1]);
            union { int4v i; short8 s; } u;
            asm("v_cvt_pk_bf16_f32 %0, %1, %2" : "=v"(u.i.x) : "v"(xv[0]), "v"(xv[1]));
            asm("v_cvt_pk_bf16_f32 %0, %1, %2" : "=v"(u.i.y) : "v"(xv[2]), "v"(xv[3]));
            asm("v_cvt_pk_bf16_f32 %0, %1, %2" : "=v"(u.i.z) : "v"(yv[0]), "v"(yv[1]));
            asm("v_cvt_pk_bf16_f32 %0, %1, %2" : "=v"(u.i.w) : "v"(yv[2]), "v"(yv[3]));
            af[mi] = u.s;
        }
        #pragma unroll
        for (int ni = 0; ni < 4; ++ni)
            bf[ni] = *(const short8*)(bs + boff[ni]);
        #pragma unroll
        for (int mi = 0; mi < 4; ++mi)
            #pragma unroll
            for (int ni = 0; ni < 4; ++ni)
                acc[mi][ni] = __builtin_amdgcn_mfma_f32_16x16x32_bf16(af[mi], bf[ni], acc[mi][ni], 0, 0, 0);
    };

    char* Ab = (char*)As;
    char* Bb = (char*)Bs;

    // prologue: fill ring slots 0,1 (12 loads in flight per wave)
    STAGE(0, Ab, Bb);
    STAGE(1, Ab + 16384, Bb + 8192);

    int cur = 0;                       // COMPUTE(t) uses slot t%3; STAGE(t+2) -> (t+2)%3 == (cur+2)%3
    #pragma unroll 1
    for (int t = 0; t < 15; ++t) {
        asm volatile("s_waitcnt vmcnt(6)" ::: "memory");   // my stage(t) loads done
        __builtin_amdgcn_s_barrier();                      // all waves: slot t%3 ready
        asm volatile("" ::: "memory");
        if (t < 14) {
            int tgt = cur == 0 ? 2 : cur - 1;              // (t+2)%3
            STAGE(t + 2, Ab + tgt * 16384, Bb + tgt * 8192);
        }
        COMPUTE(Ab + cur * 16384, Bb + cur * 8192);
        cur = cur == 2 ? 0 : cur + 1;
    }
    asm volatile("s_waitcnt vmcnt(0)" ::: "memory");       // last slot
    __builtin_amdgcn_s_barrier();
    asm volatile("" ::: "memory");
    COMPUTE(Ab + cur * 16384, Bb + cur * 8192);

    // epilogue: u = tanh(acc + qc), partial logit = sum over this wave's 64
    // cols of u*v, 16-lane reduce, store into this (bn,wn) slice.
    const float* qcb = qc + b * 512;
    float vcol[4], qcol[4];
    #pragma unroll
    for (int ni = 0; ni < 4; ++ni) {
        int c = col0 + wn * 64 + ni * 16 + (lane & 15);
        vcol[ni] = v[c];
        qcol[ni] = qcb[c];
    }
    float* pslice = part + (bn * 2 + wn) * MTOT + row0;   // unique writer slice
    int rbase = wm * 64 + 4 * (lane >> 4);
    #pragma unroll
    for (int mi = 0; mi < 4; ++mi) {
        #pragma unroll
        for (int j2 = 0; j2 < 4; ++j2) {
            float s = 0.f;
            #pragma unroll
            for (int ni = 0; ni < 4; ++ni) {
                float xx = acc[mi][ni][j2] + qcol[ni];
                float e2 = __expf(2.0f * xx);
                float tt = 1.0f - 2.0f * __builtin_amdgcn_rcpf(e2 + 1.0f);
                s += tt * vcol[ni];
            }
            s += __shfl_xor(s, 1);
            s += __shfl_xor(s, 2);
            s += __shfl_xor(s, 4);
            s += __shfl_xor(s, 8);
            if ((lane & 15) == 0)
                pslice[rbase + mi * 16 + j2] = s;
        }
    }
}

// masked softmax per batch row; sums 8 (bn,wn) partials; also zeroes ctx[b]
__global__ void softmax_kernel(const float* __restrict__ part, const int* __restrict__ length,
                               float* __restrict__ att, float* __restrict__ ctx) {
    int b = blockIdx.x;
    int len = length[b];
    int tid = threadIdx.x;     // 256
    int lane = tid & 63, wv = tid >> 6;
    const float* p0 = part + b * 2048;
    float* ab = att + b * 2048;

    ctx[b * 512 + tid] = 0.f;              // zero context (ctx_kernel atomicAdds)
    ctx[b * 512 + 256 + tid] = 0.f;

    float vals[8];
    float mymax = -3.402823466e38f;
    #pragma unroll
    for (int i = 0; i < 8; ++i) {
        int l = tid + i * 256;
        float xv = NEGV;
        if (l < len) {
            xv = 0.f;
            #pragma unroll
            for (int s = 0; s < 8; ++s)
                xv += p0[s * MTOT + l];
        }
        vals[i] = xv;
        mymax = fmaxf(mymax, xv);
    }
    #pragma unroll
    for (int m = 32; m; m >>= 1) mymax = fmaxf(mymax, __shfl_xor(mymax, m));
    __shared__ float sm[4];
    if (lane == 0) sm[wv] = mymax;
    __syncthreads();
    float bmax = fmaxf(fmaxf(sm[0], sm[1]), fmaxf(sm[2], sm[3]));

    float mysum = 0.f;
    #pragma unroll
    for (int i = 0; i < 8; ++i) {
        int l = tid + i * 256;
        float e = (l < len) ? __expf(vals[i] - bmax) : 0.f;
        vals[i] = e;
        mysum += e;
    }
    #pragma unroll
    for (int m = 32; m; m >>= 1) mysum += __shfl_xor(mysum, m);
    __shared__ float ss[4];
    if (lane == 0) ss[wv] = mysum;
    __syncthreads();
    float tot = ss[0] + ss[1] + ss[2] + ss[3];
    float inv = 1.0f / (tot + 1e-5f);
    #pragma unroll
    for (int i = 0; i < 8; ++i) {
        int l = tid + i * 256;
        ab[l] = vals[i] * inv;
    }
}

// context[b][e] = sum_l att[b][l] * enc[b][l][e]; skip masked L-chunks
__global__ void ctx_kernel(const float* __restrict__ att, const float* __restrict__ enc,
                           const int* __restrict__ length, float* __restrict__ ctx) {
    int b = blockIdx.x;        // 64
    int lc = blockIdx.y;       // 16 chunks of 128
    int len = length[b];
    int l0 = lc * 128;
    if (l0 >= len) return;
    int lim = len - l0;
    if (lim > 128) lim = 128;

    int t = threadIdx.x;       // 256 -> 2 cols each
    const float* ab = att + b * 2048 + l0;
    const float* eb = enc + ((long)(b * 2048 + l0)) * 512 + t * 2;
    float c0 = 0.f, c1 = 0.f;
    #pragma unroll 4
    for (int l = 0; l < lim; ++l) {
        float a = ab[l];
        float2v e = *(const float2v*)(eb);
        eb += 512;
        c0 += a * e.x;
        c1 += a * e.y;
    }
    atomicAdd(&ctx[b * 512 + 2 * t], c0);
    atomicAdd(&ctx[b * 512 + 2 * t + 1], c1);
}

extern "C" void kernel_launch(void* const* d_in, const int* in_sizes, int n_in,
                              void* d_out, int out_size, void* d_ws, size_t ws_size,
                              hipStream_t stream) {
    const float* enc    = (const float*)d_in[0];   // [64,2048,512]
    const float* query  = (const float*)d_in[1];   // [64,256]
    const int*   length = (const int*)d_in[2];     // [64]
    const float* W1     = (const float*)d_in[3];   // [768,512]
    const float* b1     = (const float*)d_in[4];   // [512]
    const float* v      = (const float*)d_in[5];   // [512]

    float* out = (float*)d_out;
    float* ctx = out;                // [64,512]
    float* att = out + 64 * 512;     // [64,2048]

    char* ws = (char*)d_ws;
    float* part        = (float*)ws;                               // 8*M f32 = 4MB
    float* qc          = (float*)(ws + 8 * MTOT * 4);              // 128KB
    unsigned short* Wt = (unsigned short*)(ws + 8 * MTOT * 4 + 64 * 512 * 4); // 512KB

    prep_wt_kernel<<<256, 256, 0, stream>>>(W1, Wt);
    prep_qc_kernel<<<64, 256, 0, stream>>>(query, W1, b1, qc);

    gemm_logits_kernel<<<4096, 256, 0, stream>>>(enc, Wt, qc, v, length, part);

    softmax_kernel<<<64, 256, 0, stream>>>(part, length, att, ctx);

    dim3 g3(64, 16);
    ctx_kernel<<<g3, 256, 0, stream>>>(att, enc, length, ctx);
}

// Round 6
// 145.023 us; speedup vs baseline: 1.0496x; 1.0496x over previous
//
#include <hip/hip_runtime.h>

typedef __attribute__((ext_vector_type(4))) float float4v;
typedef __attribute__((ext_vector_type(2))) float float2v;
typedef __attribute__((ext_vector_type(8))) short short8;
typedef __attribute__((ext_vector_type(4))) float f32x4;
typedef __attribute__((ext_vector_type(4))) int int4v;

#define NEGV (-1000000000.0f)

// B=64, L=2048, E=512, Q=256; M = 131072, K = 512, N = 512
#define MTOT (64 * 2048)

__device__ __forceinline__ unsigned short f2bf(float f) {
    unsigned int u = __float_as_uint(f);
    u += 0x7fffu + ((u >> 16) & 1u);   // RNE round to bf16
    return (unsigned short)(u >> 16);
}

// async global->LDS, 16B per lane, LDS dest = wave-uniform base + lane*16
__device__ __forceinline__ void gload_lds16(const void* g, void* l) {
    __builtin_amdgcn_global_load_lds(
        (__attribute__((address_space(1))) unsigned int*)(unsigned long long)(g),
        (__attribute__((address_space(3))) unsigned int*)(unsigned int)(unsigned long long)(l),
        16, 0, 0);
}

// Wt[e][c] = bf16(W1[c][e]) via LDS 32x32 tile transpose (coalesced both sides).
__global__ __launch_bounds__(256)
void prep_wt_kernel(const float* __restrict__ W1, unsigned short* __restrict__ Wt) {
    __shared__ float t[32][33];
    int bx = blockIdx.x & 15;    // c tile
    int by = blockIdx.x >> 4;    // e tile
    int tx = threadIdx.x & 31;
    int ty = threadIdx.x >> 5;   // 0..7
    #pragma unroll
    for (int i = 0; i < 4; ++i)
        t[ty + 8 * i][tx] = W1[(bx * 32 + ty + 8 * i) * 512 + by * 32 + tx];
    __syncthreads();
    #pragma unroll
    for (int i = 0; i < 4; ++i)
        Wt[(by * 32 + ty + 8 * i) * 512 + bx * 32 + tx] = f2bf(t[tx][ty + 8 * i]);
}

// qc[b][e] = b1[e] + sum_q query[b][q] * W1[512+q][e]
__global__ void prep_qc_kernel(const float* __restrict__ query, const float* __restrict__ W1,
                               const float* __restrict__ b1, float* __restrict__ qc) {
    int b = blockIdx.x;
    int e = threadIdx.x;           // 256 threads -> cols e and e+256
    float acc0 = b1[e];
    float acc1 = b1[e + 256];
    const float* w = W1 + 512 * 512;
    #pragma unroll 8
    for (int q = 0; q < 256; ++q) {
        float qv = query[b * 256 + q];
        acc0 += qv * w[q * 512 + e];
        acc1 += qv * w[q * 512 + e + 256];
    }
    qc[b * 512 + e] = acc0;
    qc[b * 512 + e + 256] = acc1;
}

// 128x128 tile, BK=32, 4 waves. A staged global->reg->cvt_pk->ds_write as
// bf16 (halves A LDS traffic vs f32; cvt off the MFMA path); B staged via
// global_load_lds. 3-slot LDS ring (48KB -> 3 blocks/CU), counted vmcnt(6):
// loads for step t+2 issued at step t, never drained to 0 in-loop.
// Both tiles XOR-swizzled ((r>>1)&3)<<4 on 64B rows: fragment reads and
// staged writes spread exactly evenly over all 32 banks.
__global__ __launch_bounds__(256, 3)
void gemm_logits_kernel(const float* __restrict__ A,            // encoded [M][512] f32
                        const unsigned short* __restrict__ Wt,  // [512 n][512 k] bf16
                        const float* __restrict__ qc,           // [64][512]
                        const float* __restrict__ v,            // [512]
                        const int* __restrict__ length,         // [64]
                        float* __restrict__ part)               // [8][M] partial logits
{
    // XCD swizzle, load-balanced: XCD x gets bm = {x, x+8, ...}; the 4 bn of
    // one bm are dispatch-adjacent on one XCD -> A-tile L2 reuse.
    int bid = blockIdx.x;
    int x = bid & 7;
    int j = bid >> 3;              // 0..511
    int bm = (j >> 2) * 8 + x;     // 0..1023 row tile
    int bn = j & 3;                // 0..3   N slice
    int b = bm >> 4;
    int l0 = (bm & 15) * 128;
    if (l0 >= length[b]) return;   // fully-masked tile

    __shared__ unsigned short As[3 * 128 * 32];  // 3 x 8 KB bf16, swizzled
    __shared__ unsigned short Bs[3 * 128 * 32];  // 3 x 8 KB bf16, swizzled

    int tid = threadIdx.x;
    int lane = tid & 63;
    int w = tid >> 6;
    int wm = w >> 1, wn = w & 1;
    long row0 = (long)bm * 128;
    int col0 = bn * 128;

    // --- A reg-staging addresses: lane owns row r = w*32+(lane>>1), half h ---
    int ar_r = w * 32 + (lane >> 1);
    int ar_h = lane & 1;
    const char* gAr = (const char*)A + (row0 + ar_r) * 2048 + ar_h * 64;
    int asw = ((ar_r >> 1) & 3) << 4;
    int awr0 = ar_r * 64 + ((ar_h * 32) ^ asw);        // byte off in A slot
    int awr1 = ar_r * 64 + ((ar_h * 32 + 16) ^ asw);

    // --- B staging: LDS linear dest, global pre-swizzled source ---
    const char* gB0;
    const char* gB1;
    {
        int off = (w * 2 + 0) * 1024 + lane * 16;
        int r = off >> 6;
        gB0 = (const char*)Wt + (long)(col0 + r) * 1024 + ((off & 63) ^ (((r >> 1) & 3) << 4));
        off = (w * 2 + 1) * 1024 + lane * 16;
        r = off >> 6;
        gB1 = (const char*)Wt + (long)(col0 + r) * 1024 + ((off & 63) ^ (((r >> 1) & 3) << 4));
    }

    // --- fragment read byte offsets (within one 8KB slot) ---
    int aoff[4], boff[4];
    int kb = 16 * (lane >> 4);
    #pragma unroll
    for (int mi = 0; mi < 4; ++mi) {
        int ar = wm * 64 + (lane & 15) + mi * 16;
        aoff[mi] = ar * 64 + (kb ^ (((ar >> 1) & 3) << 4));
    }
    #pragma unroll
    for (int ni = 0; ni < 4; ++ni) {
        int br = wn * 64 + (lane & 15) + ni * 16;
        boff[ni] = br * 64 + (kb ^ (((br >> 1) & 3) << 4));
    }

    f32x4 acc[4][4] = {};
    float4v P0, P1, P2, P3, Q0, Q1, Q2, Q3;

#define GISSUE(t, R0, R1, R2, R3, sI) do {                                   \
    const char* ga_ = gAr + (t) * 128;                                       \
    R0 = *(const float4v*)(ga_);                                             \
    R1 = *(const float4v*)(ga_ + 16);                                        \
    R2 = *(const float4v*)(ga_ + 32);                                        \
    R3 = *(const float4v*)(ga_ + 48);                                        \
    char* lb_ = (char*)Bs + (sI) * 8192 + w * 2048;                          \
    gload_lds16(gB0 + (t) * 64, lb_);                                        \
    gload_lds16(gB1 + (t) * 64, lb_ + 1024);                                 \
} while (0)

#define CVTW(R0, R1, R2, R3, sW) do {                                        \
    union { int4v i; short8 s; } u0_, u1_;                                   \
    asm("v_cvt_pk_bf16_f32 %0, %1, %2" : "=v"(u0_.i.x) : "v"(R0[0]), "v"(R0[1])); \
    asm("v_cvt_pk_bf16_f32 %0, %1, %2" : "=v"(u0_.i.y) : "v"(R0[2]), "v"(R0[3])); \
    asm("v_cvt_pk_bf16_f32 %0, %1, %2" : "=v"(u0_.i.z) : "v"(R1[0]), "v"(R1[1])); \
    asm("v_cvt_pk_bf16_f32 %0, %1, %2" : "=v"(u0_.i.w) : "v"(R1[2]), "v"(R1[3])); \
    asm("v_cvt_pk_bf16_f32 %0, %1, %2" : "=v"(u1_.i.x) : "v"(R2[0]), "v"(R2[1])); \
    asm("v_cvt_pk_bf16_f32 %0, %1, %2" : "=v"(u1_.i.y) : "v"(R2[2]), "v"(R2[3])); \
    asm("v_cvt_pk_bf16_f32 %0, %1, %2" : "=v"(u1_.i.z) : "v"(R3[0]), "v"(R3[1])); \
    asm("v_cvt_pk_bf16_f32 %0, %1, %2" : "=v"(u1_.i.w) : "v"(R3[2]), "v"(R3[3])); \
    char* aw_ = (char*)As + (sW) * 8192;                                     \
    *(short8*)(aw_ + awr0) = u0_.s;                                          \
    *(short8*)(aw_ + awr1) = u1_.s;                                          \
} while (0)

#define KCOMP(sC) do {                                                       \
    const char* as_ = (const char*)As + (sC) * 8192;                         \
    const char* bs_ = (const char*)Bs + (sC) * 8192;                         \
    short8 af_[4], bf_[4];                                                   \
    _Pragma("unroll")                                                        \
    for (int mi = 0; mi < 4; ++mi) af_[mi] = *(const short8*)(as_ + aoff[mi]); \
    _Pragma("unroll")                                                        \
    for (int ni = 0; ni < 4; ++ni) bf_[ni] = *(const short8*)(bs_ + boff[ni]); \
    _Pragma("unroll")                                                        \
    for (int mi = 0; mi < 4; ++mi)                                           \
        _Pragma("unroll")                                                    \
        for (int ni = 0; ni < 4; ++ni)                                       \
            acc[mi][ni] = __builtin_amdgcn_mfma_f32_16x16x32_bf16(af_[mi], bf_[ni], acc[mi][ni], 0, 0, 0); \
} while (0)

#define KITER(t, L0, L1, L2, L3, C0, C1, C2, C3, sC, sW, sI, ISS, VM) do {   \
    if (ISS) GISSUE((t) + 2, L0, L1, L2, L3, sI);                            \
    KCOMP(sC);                                                               \
    asm volatile("s_waitcnt vmcnt(" #VM ")" ::: "memory");                   \
    CVTW(C0, C1, C2, C3, sW);                                                \
    asm volatile("s_waitcnt lgkmcnt(0)" ::: "memory");                       \
    __builtin_amdgcn_s_barrier();                                            \
    asm volatile("" ::: "memory");                                           \
} while (0)

    // prologue: slots 0,1 in flight; cvt+write A(0); publish slot 0
    GISSUE(0, P0, P1, P2, P3, 0);
    GISSUE(1, Q0, Q1, Q2, Q3, 1);
    asm volatile("s_waitcnt vmcnt(6)" ::: "memory");   // A(0),B(0) done
    CVTW(P0, P1, P2, P3, 0);
    asm volatile("s_waitcnt lgkmcnt(0)" ::: "memory");
    __builtin_amdgcn_s_barrier();
    asm volatile("" ::: "memory");

    // main: iter t computes slot t%3, writes A(t+1) into (t+1)%3, issues (t+2)%3
    KITER(0,  P0,P1,P2,P3, Q0,Q1,Q2,Q3, 0,1,2, 1, 6);
    KITER(1,  Q0,Q1,Q2,Q3, P0,P1,P2,P3, 1,2,0, 1, 6);
    KITER(2,  P0,P1,P2,P3, Q0,Q1,Q2,Q3, 2,0,1, 1, 6);
    KITER(3,  Q0,Q1,Q2,Q3, P0,P1,P2,P3, 0,1,2, 1, 6);
    KITER(4,  P0,P1,P2,P3, Q0,Q1,Q2,Q3, 1,2,0, 1, 6);
    KITER(5,  Q0,Q1,Q2,Q3, P0,P1,P2,P3, 2,0,1, 1, 6);
    KITER(6,  P0,P1,P2,P3, Q0,Q1,Q2,Q3, 0,1,2, 1, 6);
    KITER(7,  Q0,Q1,Q2,Q3, P0,P1,P2,P3, 1,2,0, 1, 6);
    KITER(8,  P0,P1,P2,P3, Q0,Q1,Q2,Q3, 2,0,1, 1, 6);
    KITER(9,  Q0,Q1,Q2,Q3, P0,P1,P2,P3, 0,1,2, 1, 6);
    KITER(10, P0,P1,P2,P3, Q0,Q1,Q2,Q3, 1,2,0, 1, 6);
    KITER(11, Q0,Q1,Q2,Q3, P0,P1,P2,P3, 2,0,1, 1, 6);
    KITER(12, P0,P1,P2,P3, Q0,Q1,Q2,Q3, 0,1,2, 1, 6);
    KITER(13, Q0,Q1,Q2,Q3, P0,P1,P2,P3, 1,2,0, 1, 6);
    KITER(14, P0,P1,P2,P3, Q0,Q1,Q2,Q3, 2,0,1, 0, 0);   // drain: cvt A(15)->slot 0
    KCOMP(0);                                            // t=15

    // epilogue: u = tanh(acc + qc), partial logit = sum over this wave's 64
    // cols of u*v, 16-lane reduce, store into this (bn,wn) slice.
    const float* qcb = qc + b * 512;
    float vcol[4], qcol[4];
    #pragma unroll
    for (int ni = 0; ni < 4; ++ni) {
        int c = col0 + wn * 64 + ni * 16 + (lane & 15);
        vcol[ni] = v[c];
        qcol[ni] = qcb[c];
    }
    float* pslice = part + (bn * 2 + wn) * MTOT + row0;   // unique writer slice
    int rbase = wm * 64 + 4 * (lane >> 4);
    #pragma unroll
    for (int mi = 0; mi < 4; ++mi) {
        #pragma unroll
        for (int j2 = 0; j2 < 4; ++j2) {
            float s = 0.f;
            #pragma unroll
            for (int ni = 0; ni < 4; ++ni) {
                float xx = acc[mi][ni][j2] + qcol[ni];
                float e2 = __expf(2.0f * xx);
                float tt = 1.0f - 2.0f * __builtin_amdgcn_rcpf(e2 + 1.0f);
                s += tt * vcol[ni];
            }
            s += __shfl_xor(s, 1);
            s += __shfl_xor(s, 2);
            s += __shfl_xor(s, 4);
            s += __shfl_xor(s, 8);
            if ((lane & 15) == 0)
                pslice[rbase + mi * 16 + j2] = s;
        }
    }
}

// masked softmax per batch row; sums 8 (bn,wn) partials; also zeroes ctx[b]
__global__ void softmax_kernel(const float* __restrict__ part, const int* __restrict__ length,
                               float* __restrict__ att, float* __restrict__ ctx) {
    int b = blockIdx.x;
    int len = length[b];
    int tid = threadIdx.x;     // 256
    int lane = tid & 63, wv = tid >> 6;
    const float* p0 = part + b * 2048;
    float* ab = att + b * 2048;

    ctx[b * 512 + tid] = 0.f;              // zero context (ctx_kernel atomicAdds)
    ctx[b * 512 + 256 + tid] = 0.f;

    float vals[8];
    float mymax = -3.402823466e38f;
    #pragma unroll
    for (int i = 0; i < 8; ++i) {
        int l = tid + i * 256;
        float xv = NEGV;
        if (l < len) {
            xv = 0.f;
            #pragma unroll
            for (int s = 0; s < 8; ++s)
                xv += p0[s * MTOT + l];
        }
        vals[i] = xv;
        mymax = fmaxf(mymax, xv);
    }
    #pragma unroll
    for (int m = 32; m; m >>= 1) mymax = fmaxf(mymax, __shfl_xor(mymax, m));
    __shared__ float sm[4];
    if (lane == 0) sm[wv] = mymax;
    __syncthreads();
    float bmax = fmaxf(fmaxf(sm[0], sm[1]), fmaxf(sm[2], sm[3]));

    float mysum = 0.f;
    #pragma unroll
    for (int i = 0; i < 8; ++i) {
        int l = tid + i * 256;
        float e = (l < len) ? __expf(vals[i] - bmax) : 0.f;
        vals[i] = e;
        mysum += e;
    }
    #pragma unroll
    for (int m = 32; m; m >>= 1) mysum += __shfl_xor(mysum, m);
    __shared__ float ss[4];
    if (lane == 0) ss[wv] = mysum;
    __syncthreads();
    float tot = ss[0] + ss[1] + ss[2] + ss[3];
    float inv = 1.0f / (tot + 1e-5f);
    #pragma unroll
    for (int i = 0; i < 8; ++i) {
        int l = tid + i * 256;
        ab[l] = vals[i] * inv;
    }
}

// context[b][e] = sum_l att[b][l] * enc[b][l][e]; skip masked L-chunks
__global__ void ctx_kernel(const float* __restrict__ att, const float* __restrict__ enc,
                           const int* __restrict__ length, float* __restrict__ ctx) {
    int b = blockIdx.x;        // 64
    int lc = blockIdx.y;       // 16 chunks of 128
    int len = length[b];
    int l0 = lc * 128;
    if (l0 >= len) return;
    int lim = len - l0;
    if (lim > 128) lim = 128;

    int t = threadIdx.x;       // 256 -> 2 cols each
    const float* ab = att + b * 2048 + l0;
    const float* eb = enc + ((long)(b * 2048 + l0)) * 512 + t * 2;
    float c0 = 0.f, c1 = 0.f;
    #pragma unroll 4
    for (int l = 0; l < lim; ++l) {
        float a = ab[l];
        float2v e = *(const float2v*)(eb);
        eb += 512;
        c0 += a * e.x;
        c1 += a * e.y;
    }
    atomicAdd(&ctx[b * 512 + 2 * t], c0);
    atomicAdd(&ctx[b * 512 + 2 * t + 1], c1);
}

extern "C" void kernel_launch(void* const* d_in, const int* in_sizes, int n_in,
                              void* d_out, int out_size, void* d_ws, size_t ws_size,
                              hipStream_t stream) {
    const float* enc    = (const float*)d_in[0];   // [64,2048,512]
    const float* query  = (const float*)d_in[1];   // [64,256]
    const int*   length = (const int*)d_in[2];     // [64]
    const float* W1     = (const float*)d_in[3];   // [768,512]
    const float* b1     = (const float*)d_in[4];   // [512]
    const float* v      = (const float*)d_in[5];   // [512]

    float* out = (float*)d_out;
    float* ctx = out;                // [64,512]
    float* att = out + 64 * 512;     // [64,2048]

    char* ws = (char*)d_ws;
    float* part        = (float*)ws;                               // 8*M f32 = 4MB
    float* qc          = (float*)(ws + 8 * MTOT * 4);              // 128KB
    unsigned short* Wt = (unsigned short*)(ws + 8 * MTOT * 4 + 64 * 512 * 4); // 512KB

    prep_wt_kernel<<<256, 256, 0, stream>>>(W1, Wt);
    prep_qc_kernel<<<64, 256, 0, stream>>>(query, W1, b1, qc);

    gemm_logits_kernel<<<4096, 256, 0, stream>>>(enc, Wt, qc, v, length, part);

    softmax_kernel<<<64, 256, 0, stream>>>(part, length, att, ctx);

    dim3 g3(64, 16);
    ctx_kernel<<<g3, 256, 0, stream>>>(att, enc, length, ctx);
}